// Round 4
// baseline (10620.416 us; speedup 1.0000x reference)
//
#include <hip/hip_runtime.h>
#include <math.h>

// Problem constants
// B=64, LAT=512, HC=HD=1024, NB=16, S=16, E=128, NOTES=128, OUT=384, L=2
// Gate order (PyTorch): i, f, g, o as quarters of the 4096-wide gate vector.

#define BM 64
#define BN 64
#define BK 16

// Generic fp32 GEMM: C[M][N] = A1 @ W1[:, :K1].T + A2 @ W2[:, :K2].T + Add + bias1 + bias2
// W matrices are [N][K] row-major (PyTorch weight layout), so C[r][j] = sum_k A[r][k] * W[j][k].
// scatter_s >= 0: decoder-output permuted store: row r=(nb*64+bb) -> out[((bb*16+nb)*16+s)*384 + col]
__global__ __launch_bounds__(256) void gemm_f32(
    int M, int N,
    const float* __restrict__ A1, int K1, int lda1,
    const float* __restrict__ W1, int ldw1,
    const float* __restrict__ A2, int K2, int lda2,
    const float* __restrict__ W2, int ldw2,
    const float* __restrict__ Add, int ldadd,
    const float* __restrict__ bias1, const float* __restrict__ bias2,
    float* __restrict__ C, int ldc, int scatter_s)
{
    __shared__ float As[BK][BM];
    __shared__ float Ws[BK][BN];
    const int bm = blockIdx.x * BM;
    const int bn = blockIdx.y * BN;
    const int tid = threadIdx.x;
    const int ty = tid >> 4;    // 0..15 -> rows ty*4..ty*4+3
    const int tx = tid & 15;    // 0..15 -> cols tx*4..tx*4+3
    const int lr = tid >> 2;          // 0..63  (tile row / weight row)
    const int lc = (tid & 3) << 2;    // 0,4,8,12 (k offset)

    float acc[4][4] = {{0.f,0.f,0.f,0.f},{0.f,0.f,0.f,0.f},{0.f,0.f,0.f,0.f},{0.f,0.f,0.f,0.f}};

    for (int phase = 0; phase < 2; ++phase) {
        const float* Ap = phase ? A2 : A1;
        const float* Wp = phase ? W2 : W1;
        const int K   = phase ? K2 : K1;
        const int lda = phase ? lda2 : lda1;
        const int ldw = phase ? ldw2 : ldw1;
        if (Ap == nullptr || K <= 0) continue;
        for (int k0 = 0; k0 < K; k0 += BK) {
            float4 av = *(const float4*)(Ap + (size_t)(bm + lr) * lda + k0 + lc);
            float4 wv = *(const float4*)(Wp + (size_t)(bn + lr) * ldw + k0 + lc);
            __syncthreads();  // previous iteration's LDS reads done
            As[lc+0][lr] = av.x; As[lc+1][lr] = av.y; As[lc+2][lr] = av.z; As[lc+3][lr] = av.w;
            Ws[lc+0][lr] = wv.x; Ws[lc+1][lr] = wv.y; Ws[lc+2][lr] = wv.z; Ws[lc+3][lr] = wv.w;
            __syncthreads();
            #pragma unroll
            for (int k = 0; k < BK; ++k) {
                float4 a = *(const float4*)&As[k][ty << 2];
                float4 w = *(const float4*)&Ws[k][tx << 2];
                acc[0][0] = fmaf(a.x, w.x, acc[0][0]);
                acc[0][1] = fmaf(a.x, w.y, acc[0][1]);
                acc[0][2] = fmaf(a.x, w.z, acc[0][2]);
                acc[0][3] = fmaf(a.x, w.w, acc[0][3]);
                acc[1][0] = fmaf(a.y, w.x, acc[1][0]);
                acc[1][1] = fmaf(a.y, w.y, acc[1][1]);
                acc[1][2] = fmaf(a.y, w.z, acc[1][2]);
                acc[1][3] = fmaf(a.y, w.w, acc[1][3]);
                acc[2][0] = fmaf(a.z, w.x, acc[2][0]);
                acc[2][1] = fmaf(a.z, w.y, acc[2][1]);
                acc[2][2] = fmaf(a.z, w.z, acc[2][2]);
                acc[2][3] = fmaf(a.z, w.w, acc[2][3]);
                acc[3][0] = fmaf(a.w, w.x, acc[3][0]);
                acc[3][1] = fmaf(a.w, w.y, acc[3][1]);
                acc[3][2] = fmaf(a.w, w.z, acc[3][2]);
                acc[3][3] = fmaf(a.w, w.w, acc[3][3]);
            }
        }
    }

    #pragma unroll
    for (int i = 0; i < 4; ++i) {
        const int row = bm + (ty << 2) + i;
        #pragma unroll
        for (int j = 0; j < 4; ++j) {
            const int col = bn + (tx << 2) + j;
            float v = acc[i][j];
            if (bias1) v += bias1[col];
            if (bias2) v += bias2[col];
            if (Add)   v += Add[(size_t)row * ldadd + col];
            if (scatter_s >= 0) {
                // row r = nb*64+bb ; out[((bb*16+nb)*16+s)*384 + col]
                const int bb = row & 63, nb = row >> 6;
                C[(size_t)(((bb * 16 + nb) * 16 + scatter_s)) * 384 + col] = v;
            } else {
                C[(size_t)row * ldc + col] = v;
            }
        }
    }
}

// LSTM cell pointwise: gates [M][4096] (i,f,g,o), c/h [M][1024]; optional extra h copy.
__global__ __launch_bounds__(256) void lstm_cell(
    const float* __restrict__ g, float* __restrict__ c,
    float* __restrict__ h, float* __restrict__ hcopy, int M)
{
    const int idx = blockIdx.x * blockDim.x + threadIdx.x;
    if (idx >= (M << 10)) return;
    const int r = idx >> 10, k = idx & 1023;
    const float* gr = g + ((size_t)r << 12);
    const float gi = gr[k], gf = gr[k + 1024], gg = gr[k + 2048], go = gr[k + 3072];
    const float si = 1.f / (1.f + expf(-gi));
    const float sf = 1.f / (1.f + expf(-gf));
    const float so = 1.f / (1.f + expf(-go));
    const float cn = sf * c[idx] + si * tanhf(gg);
    const float hn = so * tanhf(cn);
    c[idx] = cn;
    h[idx] = hn;
    if (hcopy) hcopy[idx] = hn;
}

// ini [64][4096] -> hc/cc [2][64][1024]  (j = s2*2048 + l*1024 + k)
__global__ __launch_bounds__(256) void scatter_ini(
    const float* __restrict__ I, float* __restrict__ hc, float* __restrict__ cc)
{
    const int idx = blockIdx.x * blockDim.x + threadIdx.x;  // 2*64*1024
    if (idx >= 131072) return;
    const int k = idx & 1023, b = (idx >> 10) & 63, l = idx >> 16;
    const float* row = I + (size_t)b * 4096;
    hc[idx] = row[(l << 10) + k];
    cc[idx] = row[2048 + (l << 10) + k];
}

// di [1024][4096] -> hd0/hd1/cd0/cd1 [1024][1024]
__global__ __launch_bounds__(256) void scatter_di(
    const float* __restrict__ D, float* __restrict__ hd0, float* __restrict__ cd0,
    float* __restrict__ hd1, float* __restrict__ cd1)
{
    const int idx = blockIdx.x * blockDim.x + threadIdx.x;  // 1024*1024
    if (idx >= 1048576) return;
    const int k = idx & 1023, r = idx >> 10;
    const float* row = D + ((size_t)r << 12);
    hd0[idx] = row[k];
    hd1[idx] = row[1024 + k];
    cd0[idx] = row[2048 + k];
    cd1[idx] = row[3072 + k];
}

// prevf[s][r=nb*64+bb][n] = (t==0) ? 0 : (float)tp[bb][t-1][n],  t = nb*16 + s
__global__ __launch_bounds__(256) void build_prev(
    const int* __restrict__ tp, float* __restrict__ prevf)
{
    const int idx = blockIdx.x * blockDim.x + threadIdx.x;  // 16*1024*128
    if (idx >= 2097152) return;
    const int n = idx & 127;
    const int r = (idx >> 7) & 1023;
    const int s = idx >> 17;
    const int nb = r >> 6, bb = r & 63;
    const int t = nb * 16 + s;
    float v = 0.f;
    if (t > 0) v = (float)tp[(size_t)bb * 32768 + (size_t)(t - 1) * 128 + n];
    prevf[idx] = v;
}

extern "C" void kernel_launch(void* const* d_in, const int* in_sizes, int n_in,
                              void* d_out, int out_size, void* d_ws, size_t ws_size,
                              hipStream_t stream)
{
    (void)in_sizes; (void)n_in; (void)out_size; (void)ws_size;
    const float* z      = (const float*)d_in[0];
    const int*   tp     = (const int*)  d_in[1];
    const float* w_zc   = (const float*)d_in[2];
    const float* b_zc   = (const float*)d_in[3];
    // d_in[4] = c_wih0: multiplies zero input -> unused
    const float* c_whh0 = (const float*)d_in[5];
    const float* c_bih0 = (const float*)d_in[6];
    const float* c_bhh0 = (const float*)d_in[7];
    const float* c_wih1 = (const float*)d_in[8];
    const float* c_whh1 = (const float*)d_in[9];
    const float* c_bih1 = (const float*)d_in[10];
    const float* c_bhh1 = (const float*)d_in[11];
    const float* np_w   = (const float*)d_in[12];
    const float* np_b   = (const float*)d_in[13];
    const float* cd_w   = (const float*)d_in[14];
    const float* cd_b   = (const float*)d_in[15];
    const float* d_wih0 = (const float*)d_in[16];
    const float* d_whh0 = (const float*)d_in[17];
    const float* d_bih0 = (const float*)d_in[18];
    const float* d_bhh0 = (const float*)d_in[19];
    const float* d_wih1 = (const float*)d_in[20];
    const float* d_whh1 = (const float*)d_in[21];
    const float* d_bih1 = (const float*)d_in[22];
    const float* d_bhh1 = (const float*)d_in[23];
    const float* op_w   = (const float*)d_in[24];
    const float* op_b   = (const float*)d_in[25];
    float* out = (float*)d_out;

    // Workspace layout (floats). Total ~18.4M floats = ~73.4 MB.
    float* ws      = (float*)d_ws;
    float* hc      = ws;                  // [2][64][1024]
    float* cc      = hc + 131072;         // [2][64][1024]
    float* cond    = cc + 131072;         // [16][64][1024] == [1024][1024] (row = nb*64+bb)
    float* cg      = cond + 1048576;      // [64][4096] conductor gates / ini scratch
    float* barpart = cg + 262144;         // [1024][4096]
    float* emb     = barpart + 4194304;   // [16][1024][128]
    float* prevf   = emb + 2097152;       // [16][1024][128]
    float* hd0     = prevf + 2097152;     // [1024][1024]
    float* cd0     = hd0 + 1048576;
    float* hd1     = cd0 + 1048576;
    float* cd1     = hd1 + 1048576;
    float* dg      = cd1 + 1048576;       // [1024][4096] decoder gates / di scratch

    auto gemm = [&](int M, int N,
                    const float* A1, int K1, int lda1, const float* W1, int ldw1,
                    const float* A2, int K2, int lda2, const float* W2, int ldw2,
                    const float* Add, int ldadd,
                    const float* b1, const float* b2,
                    float* Cp, int ldc, int ss) {
        dim3 grid(M / BM, N / BN);
        gemm_f32<<<grid, dim3(256), 0, stream>>>(M, N, A1, K1, lda1, W1, ldw1,
                                                 A2, K2, lda2, W2, ldw2,
                                                 Add, ldadd, b1, b2, Cp, ldc, ss);
    };

    // 1) ini = z @ w_zc.T + b_zc  -> cg[64][4096] -> scatter to conductor h/c
    gemm(64, 4096, z, 512, 512, w_zc, 512,
         nullptr, 0, 0, nullptr, 0, nullptr, 0, b_zc, nullptr, cg, 4096, -1);
    scatter_ini<<<512, 256, 0, stream>>>(cg, hc, cc);

    // 2) teacher-forced prev -> embedding (parallel work, independent of conductor)
    build_prev<<<8192, 256, 0, stream>>>(tp, prevf);
    gemm(16384, 128, prevf, 128, 128, np_w, 128,
         nullptr, 0, 0, nullptr, 0, nullptr, 0, np_b, nullptr, emb, 128, -1);

    // 3) Conductor: 16 steps, 2 layers, batch 64. Layer-0 input is zeros -> recurrent GEMM only.
    for (int t = 0; t < 16; ++t) {
        gemm(64, 4096, hc, 1024, 1024, c_whh0, 1024,
             nullptr, 0, 0, nullptr, 0, nullptr, 0, c_bih0, c_bhh0, cg, 4096, -1);
        lstm_cell<<<256, 256, 0, stream>>>(cg, cc, hc, nullptr, 64);
        gemm(64, 4096, hc, 1024, 1024, c_wih1, 1024,
             hc + 65536, 1024, 1024, c_whh1, 1024,
             nullptr, 0, c_bih1, c_bhh1, cg, 4096, -1);
        lstm_cell<<<256, 256, 0, stream>>>(cg, cc + 65536, hc + 65536, cond + t * 65536, 64);
    }

    // 4) Decoder initial states: di = cond @ cd_w.T + cd_b -> scatter
    gemm(1024, 4096, cond, 1024, 1024, cd_w, 1024,
         nullptr, 0, 0, nullptr, 0, nullptr, 0, cd_b, nullptr, dg, 4096, -1);
    scatter_di<<<4096, 256, 0, stream>>>(dg, hd0, cd0, hd1, cd1);

    // 5) barpart = cond @ d_wih0[:,128:].T + (bih0+bhh0)  (time-invariant part of layer-0 gates)
    gemm(1024, 4096, cond, 1024, 1024, d_wih0 + 128, 1152,
         nullptr, 0, 0, nullptr, 0, nullptr, 0, d_bih0, d_bhh0, barpart, 4096, -1);

    // 6) Decoder: 16 steps, 2 layers, batch 1024.
    for (int s = 0; s < 16; ++s) {
        // layer0 gates = emb[s] @ wih0[:, :128].T + hd0 @ whh0.T + barpart
        gemm(1024, 4096, emb + (size_t)s * 131072, 128, 128, d_wih0, 1152,
             hd0, 1024, 1024, d_whh0, 1024,
             barpart, 4096, nullptr, nullptr, dg, 4096, -1);
        lstm_cell<<<4096, 256, 0, stream>>>(dg, cd0, hd0, nullptr, 1024);
        // layer1 gates = hd0 @ wih1.T + hd1 @ whh1.T + biases
        gemm(1024, 4096, hd0, 1024, 1024, d_wih1, 1024,
             hd1, 1024, 1024, d_whh1, 1024,
             nullptr, 0, d_bih1, d_bhh1, dg, 4096, -1);
        lstm_cell<<<4096, 256, 0, stream>>>(dg, cd1, hd1, nullptr, 1024);
        // output projection with permuted store directly into d_out
        gemm(1024, 384, hd1, 1024, 1024, op_w, 1024,
             nullptr, 0, 0, nullptr, 0, nullptr, 0, op_b, nullptr, out, 384, s);
    }
}

// Round 6
// 6010.264 us; speedup vs baseline: 1.7670x; 1.7670x over previous
//
#include <hip/hip_runtime.h>
#include <math.h>

// B=64, LAT=512, HC=HD=1024, NB=16, S=16, E=128, NOTES=128, OUT=384, L=2
// Gate order (PyTorch): i,f,g,o quarters of the 4096-wide gate vector.
//
// Strategy: all GEMMs on MFMA (16x16x32 bf16) with SPLIT-BF16 operands:
//   x ~= hi + lo,  hi = bf16(x), lo = bf16(x - hi)
//   A@W ~= Ah@Wh + Ah@Wl + Al@Wh   (3 MFMAs, error ~2^-16 rel => fp32-like)
// Weights split once per launch into ws; states split on the fly by cell kernels.
// If ws_size is too small for the split buffers, fall back to the proven fp32 path.

typedef __attribute__((ext_vector_type(8))) short s16x8;
typedef __attribute__((ext_vector_type(4))) float f32x4;

__device__ inline unsigned short f2bu(float f) {   // RNE f32->bf16
    unsigned u = __float_as_uint(f);
    unsigned r = u + 0x7fff + ((u >> 16) & 1);
    return (unsigned short)(r >> 16);
}
__device__ inline float bu2f(unsigned short h) { return __uint_as_float(((unsigned)h) << 16); }

// ---------------------------------------------------------------------------
// MFMA GEMM: C[M][N] = A1@W1[:, :K1].T + A2@W2.T + Add + b1 + b2
// A,W given as split bf16 (hi,lo) arrays, [rows][ld] each.
// Tile: BM=64 x BN=128, BK=32, 256 threads = 4 waves (wave w: cols w*32..+32).
// LDS: A 64 rows x 128B (hi[32]|lo[32] bf16), W 128 rows x 128B; XOR swizzle
//      byte ^= (row&7)<<4 on 16B slots -> conflict-free b128 reads/writes.
// mode: 0 = fp32 C[r*ldc+col]; 1 = split store to Chi/Clo; 2 = scatter to out.
__global__ __launch_bounds__(256) void gemm_mfma(
    int M, int N,
    const unsigned short* __restrict__ A1h, const unsigned short* __restrict__ A1l, int K1, int lda1,
    const unsigned short* __restrict__ W1h, const unsigned short* __restrict__ W1l, int ldw1,
    const unsigned short* __restrict__ A2h, const unsigned short* __restrict__ A2l, int K2, int lda2,
    const unsigned short* __restrict__ W2h, const unsigned short* __restrict__ W2l, int ldw2,
    const float* __restrict__ Add, int ldadd,
    const float* __restrict__ b1, const float* __restrict__ b2,
    float* __restrict__ C, int ldc,
    unsigned short* __restrict__ Chi, unsigned short* __restrict__ Clo,
    int mode, int scatter_s)
{
    __shared__ __align__(16) unsigned short lds_u[(64 + 128) * 64];
    char* ldsb = (char*)lds_u;              // A at 0 (8KB), W at 8192 (16KB)

    const int tid = threadIdx.x;
    const int lane = tid & 63;
    const int wv = tid >> 6;
    const int bm = blockIdx.x * 64;
    const int bn = blockIdx.y * 128;

    // staging assignments (constant per thread)
    const int rowA = tid >> 2;              // 0..63
    const int hA = (tid & 3) * 2;           // halves hA, hA+1 (same hi/lo buffer)
    const bool aIsLo = hA >= 4;
    const int koffA = (hA & 3) * 8;
    const int swA = (rowA & 7) << 4;
    const int ldsA0 = rowA * 128 + ((hA * 16) ^ swA);
    const int ldsA1 = rowA * 128 + (((hA + 1) * 16) ^ swA);

    const int rowB = tid >> 1;              // 0..127
    const bool bIsLo = (tid & 1) != 0;
    const int swB = (rowB & 7) << 4;
    const int sB = bIsLo ? 4 : 0;
    const int ldsB0 = 8192 + rowB * 128 + (((sB + 0) * 16) ^ swB);
    const int ldsB1 = 8192 + rowB * 128 + (((sB + 1) * 16) ^ swB);
    const int ldsB2 = 8192 + rowB * 128 + (((sB + 2) * 16) ^ swB);
    const int ldsB3 = 8192 + rowB * 128 + (((sB + 3) * 16) ^ swB);

    f32x4 acc[4][2];
#pragma unroll
    for (int m = 0; m < 4; ++m)
#pragma unroll
        for (int n = 0; n < 2; ++n) acc[m][n] = (f32x4)0.0f;

    const int fr = lane & 15;               // frag row/col
    const int kc = lane >> 4;               // k-chunk 0..3

    const int ktot = K1 + K2;
    for (int k0 = 0; k0 < ktot; k0 += 32) {
        const bool ph2 = (k0 >= K1);
        const unsigned short* Ah = ph2 ? A2h : A1h;
        const unsigned short* Al = ph2 ? A2l : A1l;
        const unsigned short* Wh = ph2 ? W2h : W1h;
        const unsigned short* Wl = ph2 ? W2l : W1l;
        const int lda = ph2 ? lda2 : lda1;
        const int ldw = ph2 ? ldw2 : ldw1;
        const int kk = ph2 ? (k0 - K1) : k0;

        // issue global loads (overlap with barrier wait)
        const unsigned short* ap = (aIsLo ? Al : Ah) + (size_t)(bm + rowA) * lda + kk + koffA;
        s16x8 va0 = *(const s16x8*)(ap);
        s16x8 va1 = *(const s16x8*)(ap + 8);
        const unsigned short* bp = (bIsLo ? Wl : Wh) + (size_t)(bn + rowB) * ldw + kk;
        s16x8 vb0 = *(const s16x8*)(bp);
        s16x8 vb1 = *(const s16x8*)(bp + 8);
        s16x8 vb2 = *(const s16x8*)(bp + 16);
        s16x8 vb3 = *(const s16x8*)(bp + 24);

        __syncthreads();                    // previous iter's LDS reads done
        *(s16x8*)(ldsb + ldsA0) = va0;
        *(s16x8*)(ldsb + ldsA1) = va1;
        *(s16x8*)(ldsb + ldsB0) = vb0;
        *(s16x8*)(ldsb + ldsB1) = vb1;
        *(s16x8*)(ldsb + ldsB2) = vb2;
        *(s16x8*)(ldsb + ldsB3) = vb3;
        __syncthreads();

        s16x8 ah[4], al[4], bh[2], bl[2];
#pragma unroll
        for (int m = 0; m < 4; ++m) {
            const int row = m * 16 + fr;
            const int sw = (row & 7) << 4;
            const int base = row * 128;
            ah[m] = *(const s16x8*)(ldsb + base + ((kc * 16) ^ sw));
            al[m] = *(const s16x8*)(ldsb + base + (((kc + 4) * 16) ^ sw));
        }
#pragma unroll
        for (int n = 0; n < 2; ++n) {
            const int row = wv * 32 + n * 16 + fr;
            const int sw = (row & 7) << 4;
            const int base = 8192 + row * 128;
            bh[n] = *(const s16x8*)(ldsb + base + ((kc * 16) ^ sw));
            bl[n] = *(const s16x8*)(ldsb + base + (((kc + 4) * 16) ^ sw));
        }
#pragma unroll
        for (int m = 0; m < 4; ++m)
#pragma unroll
            for (int n = 0; n < 2; ++n) {
                acc[m][n] = __builtin_amdgcn_mfma_f32_16x16x32_bf16(ah[m], bh[n], acc[m][n], 0, 0, 0);
                acc[m][n] = __builtin_amdgcn_mfma_f32_16x16x32_bf16(al[m], bh[n], acc[m][n], 0, 0, 0);
                acc[m][n] = __builtin_amdgcn_mfma_f32_16x16x32_bf16(ah[m], bl[n], acc[m][n], 0, 0, 0);
            }
    }

    // epilogue: C/D layout col=lane&15, row=(lane>>4)*4+reg
#pragma unroll
    for (int m = 0; m < 4; ++m)
#pragma unroll
        for (int n = 0; n < 2; ++n) {
            f32x4 v4 = acc[m][n];
#pragma unroll
            for (int q = 0; q < 4; ++q) {
                const int rl = m * 16 + kc * 4 + q;
                const int cl = wv * 32 + n * 16 + fr;
                const int r = bm + rl, col = bn + cl;
                float v = v4[q];
                if (b1) v += b1[col];
                if (b2) v += b2[col];
                if (Add) v += Add[(size_t)r * ldadd + col];
                if (mode == 0) {
                    C[(size_t)r * ldc + col] = v;
                } else if (mode == 1) {
                    unsigned short h = f2bu(v);
                    Chi[(size_t)r * ldc + col] = h;
                    Clo[(size_t)r * ldc + col] = f2bu(v - bu2f(h));
                } else {
                    const int bb = r & 63, nb = r >> 6;
                    C[(size_t)(((bb * 16 + nb) * 16 + scatter_s)) * 384 + col] = v;
                }
            }
        }
}

// ---------------------------------------------------------------------------
// split fp32 -> (hi,lo) bf16. src strided [R][ldsrc], take C cols from c0.
__global__ __launch_bounds__(256) void split_pack(
    const float* __restrict__ src, int ldsrc, int c0, long total, int C,
    unsigned short* __restrict__ hi, unsigned short* __restrict__ lo)
{
    long i = ((long)blockIdx.x * 256 + threadIdx.x) * 4;
    if (i >= total) return;
    int r = (int)(i / C), c = (int)(i % C);
    float4 v = *(const float4*)(src + (size_t)r * ldsrc + c0 + c);
#pragma unroll
    for (int j = 0; j < 4; ++j) {
        float x = (&v.x)[j];
        unsigned short h = f2bu(x);
        hi[i + j] = h;
        lo[i + j] = f2bu(x - bu2f(h));
    }
}

// LSTM pointwise with split-bf16 h output (+ optional copy)
__global__ __launch_bounds__(256) void lstm_cell_split(
    const float* __restrict__ g, float* __restrict__ c,
    unsigned short* __restrict__ hhi, unsigned short* __restrict__ hlo,
    unsigned short* __restrict__ cpyh, unsigned short* __restrict__ cpyl, int M)
{
    const int idx = blockIdx.x * blockDim.x + threadIdx.x;
    if (idx >= (M << 10)) return;
    const int r = idx >> 10, k = idx & 1023;
    const float* gr = g + ((size_t)r << 12);
    const float gi = gr[k], gf = gr[k + 1024], gg = gr[k + 2048], go = gr[k + 3072];
    const float si = 1.f / (1.f + expf(-gi));
    const float sf = 1.f / (1.f + expf(-gf));
    const float so = 1.f / (1.f + expf(-go));
    const float cn = sf * c[idx] + si * tanhf(gg);
    const float hn = so * tanhf(cn);
    c[idx] = cn;
    unsigned short h = f2bu(hn);
    unsigned short l = f2bu(hn - bu2f(h));
    hhi[idx] = h; hlo[idx] = l;
    if (cpyh) { cpyh[idx] = h; cpyl[idx] = l; }
}

// ini [64][4096] -> hc split [2][64][1024], cc fp32
__global__ __launch_bounds__(256) void scatter_ini_split(
    const float* __restrict__ I, unsigned short* __restrict__ hchi,
    unsigned short* __restrict__ hclo, float* __restrict__ cc)
{
    const int idx = blockIdx.x * blockDim.x + threadIdx.x;
    if (idx >= 131072) return;
    const int k = idx & 1023, b = (idx >> 10) & 63, l = idx >> 16;
    const float* row = I + (size_t)b * 4096;
    float hv = row[(l << 10) + k];
    unsigned short h = f2bu(hv);
    hchi[idx] = h; hclo[idx] = f2bu(hv - bu2f(h));
    cc[idx] = row[2048 + (l << 10) + k];
}

// di [1024][4096] -> hd0/hd1 split, cd0/cd1 fp32
__global__ __launch_bounds__(256) void scatter_di_split(
    const float* __restrict__ D,
    unsigned short* __restrict__ h0h, unsigned short* __restrict__ h0l,
    unsigned short* __restrict__ h1h, unsigned short* __restrict__ h1l,
    float* __restrict__ cd0, float* __restrict__ cd1)
{
    const int idx = blockIdx.x * blockDim.x + threadIdx.x;
    if (idx >= 1048576) return;
    const int k = idx & 1023, r = idx >> 10;
    const float* row = D + ((size_t)r << 12);
    float v0 = row[k], v1 = row[1024 + k];
    unsigned short a = f2bu(v0); h0h[idx] = a; h0l[idx] = f2bu(v0 - bu2f(a));
    unsigned short b = f2bu(v1); h1h[idx] = b; h1l[idx] = f2bu(v1 - bu2f(b));
    cd0[idx] = row[2048 + k];
    cd1[idx] = row[3072 + k];
}

// prev (teacher-forced, integer 0..2 -> exact bf16, lo = 0)
__global__ __launch_bounds__(256) void build_prev_b(
    const int* __restrict__ tp, unsigned short* __restrict__ ph, unsigned short* __restrict__ pl)
{
    const int idx = blockIdx.x * blockDim.x + threadIdx.x;
    if (idx >= 2097152) return;
    const int n = idx & 127;
    const int r = (idx >> 7) & 1023;
    const int s = idx >> 17;
    const int nb = r >> 6, bb = r & 63;
    const int t = nb * 16 + s;
    float v = 0.f;
    if (t > 0) v = (float)tp[(size_t)bb * 32768 + (size_t)(t - 1) * 128 + n];
    ph[idx] = f2bu(v);
    pl[idx] = 0;
}

// ===========================================================================
// Fallback fp32 path (proven baseline)
#define BM 64
#define BN 64
#define BK 16

__global__ __launch_bounds__(256) void gemm_f32(
    int M, int N,
    const float* __restrict__ A1, int K1, int lda1,
    const float* __restrict__ W1, int ldw1,
    const float* __restrict__ A2, int K2, int lda2,
    const float* __restrict__ W2, int ldw2,
    const float* __restrict__ Add, int ldadd,
    const float* __restrict__ bias1, const float* __restrict__ bias2,
    float* __restrict__ C, int ldc, int scatter_s)
{
    __shared__ float As[BK][BM];
    __shared__ float Ws[BK][BN];
    const int bm = blockIdx.x * BM;
    const int bn = blockIdx.y * BN;
    const int tid = threadIdx.x;
    const int ty = tid >> 4;
    const int tx = tid & 15;
    const int lr = tid >> 2;
    const int lc = (tid & 3) << 2;

    float acc[4][4] = {{0.f,0.f,0.f,0.f},{0.f,0.f,0.f,0.f},{0.f,0.f,0.f,0.f},{0.f,0.f,0.f,0.f}};

    for (int phase = 0; phase < 2; ++phase) {
        const float* Ap = phase ? A2 : A1;
        const float* Wp = phase ? W2 : W1;
        const int K   = phase ? K2 : K1;
        const int lda = phase ? lda2 : lda1;
        const int ldw = phase ? ldw2 : ldw1;
        if (Ap == nullptr || K <= 0) continue;
        for (int k0 = 0; k0 < K; k0 += BK) {
            float4 av = *(const float4*)(Ap + (size_t)(bm + lr) * lda + k0 + lc);
            float4 wv = *(const float4*)(Wp + (size_t)(bn + lr) * ldw + k0 + lc);
            __syncthreads();
            As[lc+0][lr] = av.x; As[lc+1][lr] = av.y; As[lc+2][lr] = av.z; As[lc+3][lr] = av.w;
            Ws[lc+0][lr] = wv.x; Ws[lc+1][lr] = wv.y; Ws[lc+2][lr] = wv.z; Ws[lc+3][lr] = wv.w;
            __syncthreads();
            #pragma unroll
            for (int k = 0; k < BK; ++k) {
                float4 a = *(const float4*)&As[k][ty << 2];
                float4 w = *(const float4*)&Ws[k][tx << 2];
                acc[0][0] = fmaf(a.x, w.x, acc[0][0]);
                acc[0][1] = fmaf(a.x, w.y, acc[0][1]);
                acc[0][2] = fmaf(a.x, w.z, acc[0][2]);
                acc[0][3] = fmaf(a.x, w.w, acc[0][3]);
                acc[1][0] = fmaf(a.y, w.x, acc[1][0]);
                acc[1][1] = fmaf(a.y, w.y, acc[1][1]);
                acc[1][2] = fmaf(a.y, w.z, acc[1][2]);
                acc[1][3] = fmaf(a.y, w.w, acc[1][3]);
                acc[2][0] = fmaf(a.z, w.x, acc[2][0]);
                acc[2][1] = fmaf(a.z, w.y, acc[2][1]);
                acc[2][2] = fmaf(a.z, w.z, acc[2][2]);
                acc[2][3] = fmaf(a.z, w.w, acc[2][3]);
                acc[3][0] = fmaf(a.w, w.x, acc[3][0]);
                acc[3][1] = fmaf(a.w, w.y, acc[3][1]);
                acc[3][2] = fmaf(a.w, w.z, acc[3][2]);
                acc[3][3] = fmaf(a.w, w.w, acc[3][3]);
            }
        }
    }

    #pragma unroll
    for (int i = 0; i < 4; ++i) {
        const int row = bm + (ty << 2) + i;
        #pragma unroll
        for (int j = 0; j < 4; ++j) {
            const int col = bn + (tx << 2) + j;
            float v = acc[i][j];
            if (bias1) v += bias1[col];
            if (bias2) v += bias2[col];
            if (Add)   v += Add[(size_t)row * ldadd + col];
            if (scatter_s >= 0) {
                const int bb = row & 63, nb = row >> 6;
                C[(size_t)(((bb * 16 + nb) * 16 + scatter_s)) * 384 + col] = v;
            } else {
                C[(size_t)row * ldc + col] = v;
            }
        }
    }
}

__global__ __launch_bounds__(256) void lstm_cell(
    const float* __restrict__ g, float* __restrict__ c,
    float* __restrict__ h, float* __restrict__ hcopy, int M)
{
    const int idx = blockIdx.x * blockDim.x + threadIdx.x;
    if (idx >= (M << 10)) return;
    const int r = idx >> 10, k = idx & 1023;
    const float* gr = g + ((size_t)r << 12);
    const float gi = gr[k], gf = gr[k + 1024], gg = gr[k + 2048], go = gr[k + 3072];
    const float si = 1.f / (1.f + expf(-gi));
    const float sf = 1.f / (1.f + expf(-gf));
    const float so = 1.f / (1.f + expf(-go));
    const float cn = sf * c[idx] + si * tanhf(gg);
    const float hn = so * tanhf(cn);
    c[idx] = cn;
    h[idx] = hn;
    if (hcopy) hcopy[idx] = hn;
}

__global__ __launch_bounds__(256) void scatter_ini(
    const float* __restrict__ I, float* __restrict__ hc, float* __restrict__ cc)
{
    const int idx = blockIdx.x * blockDim.x + threadIdx.x;
    if (idx >= 131072) return;
    const int k = idx & 1023, b = (idx >> 10) & 63, l = idx >> 16;
    const float* row = I + (size_t)b * 4096;
    hc[idx] = row[(l << 10) + k];
    cc[idx] = row[2048 + (l << 10) + k];
}

__global__ __launch_bounds__(256) void scatter_di(
    const float* __restrict__ D, float* __restrict__ hd0, float* __restrict__ cd0,
    float* __restrict__ hd1, float* __restrict__ cd1)
{
    const int idx = blockIdx.x * blockDim.x + threadIdx.x;
    if (idx >= 1048576) return;
    const int k = idx & 1023, r = idx >> 10;
    const float* row = D + ((size_t)r << 12);
    hd0[idx] = row[k];
    hd1[idx] = row[1024 + k];
    cd0[idx] = row[2048 + k];
    cd1[idx] = row[3072 + k];
}

__global__ __launch_bounds__(256) void build_prev(
    const int* __restrict__ tp, float* __restrict__ prevf)
{
    const int idx = blockIdx.x * blockDim.x + threadIdx.x;
    if (idx >= 2097152) return;
    const int n = idx & 127;
    const int r = (idx >> 7) & 1023;
    const int s = idx >> 17;
    const int nb = r >> 6, bb = r & 63;
    const int t = nb * 16 + s;
    float v = 0.f;
    if (t > 0) v = (float)tp[(size_t)bb * 32768 + (size_t)(t - 1) * 128 + n];
    prevf[idx] = v;
}

// ===========================================================================
extern "C" void kernel_launch(void* const* d_in, const int* in_sizes, int n_in,
                              void* d_out, int out_size, void* d_ws, size_t ws_size,
                              hipStream_t stream)
{
    (void)in_sizes; (void)n_in; (void)out_size;
    const float* z      = (const float*)d_in[0];
    const int*   tp     = (const int*)  d_in[1];
    const float* w_zc   = (const float*)d_in[2];
    const float* b_zc   = (const float*)d_in[3];
    const float* c_whh0 = (const float*)d_in[5];
    const float* c_bih0 = (const float*)d_in[6];
    const float* c_bhh0 = (const float*)d_in[7];
    const float* c_wih1 = (const float*)d_in[8];
    const float* c_whh1 = (const float*)d_in[9];
    const float* c_bih1 = (const float*)d_in[10];
    const float* c_bhh1 = (const float*)d_in[11];
    const float* np_w   = (const float*)d_in[12];
    const float* np_b   = (const float*)d_in[13];
    const float* cd_w   = (const float*)d_in[14];
    const float* cd_b   = (const float*)d_in[15];
    const float* d_wih0 = (const float*)d_in[16];
    const float* d_whh0 = (const float*)d_in[17];
    const float* d_bih0 = (const float*)d_in[18];
    const float* d_bhh0 = (const float*)d_in[19];
    const float* d_wih1 = (const float*)d_in[20];
    const float* d_whh1 = (const float*)d_in[21];
    const float* d_bih1 = (const float*)d_in[22];
    const float* d_bhh1 = (const float*)d_in[23];
    const float* op_w   = (const float*)d_in[24];
    const float* op_b   = (const float*)d_in[25];
    float* out = (float*)d_out;

    // ---- workspace layout for MFMA path (bytes) ----
    size_t o = 0;
    auto alloc = [&](size_t bytes) { size_t r = o; o = (o + bytes + 255) & ~(size_t)255; return r; };
    const size_t oCW0 = alloc((size_t)4096*1024*4);   // split buffers: 2*R*C ushorts = R*C*4 B
    const size_t oCW1 = alloc((size_t)4096*1024*4);
    const size_t oCW2 = alloc((size_t)4096*1024*4);
    const size_t oWZC = alloc((size_t)4096*512*4);    // later re-used for DWIH0E + OPW
    const size_t oNPW = alloc((size_t)128*128*4);
    const size_t oZS  = alloc((size_t)64*512*4);
    const size_t oCDW = alloc((size_t)4096*1024*4);
    const size_t oD0R = alloc((size_t)4096*1024*4);
    const size_t oCG  = alloc((size_t)64*4096*4);
    const size_t oCC  = alloc((size_t)2*64*1024*4);
    const size_t oHC  = alloc((size_t)2*64*1024*4);   // split
    const size_t oCND = alloc((size_t)1024*1024*4);   // split
    const size_t oPRV = alloc((size_t)16*1024*128*4); // split (lo = 0)
    const size_t oEMB = alloc((size_t)16*1024*128*4); // split
    const size_t oBRP = alloc((size_t)1024*4096*4);
    const size_t oDG  = alloc((size_t)1024*4096*4);
    const size_t oHD0 = alloc((size_t)1024*1024*4);   // split
    const size_t oHD1 = alloc((size_t)1024*1024*4);   // split
    const size_t oCD0 = alloc((size_t)1024*1024*4);
    const size_t oCD1 = alloc((size_t)1024*1024*4);
    const size_t need = o;

    if (ws_size >= need) {
        // ================= MFMA split-bf16 path =================
        char* ws = (char*)d_ws;
        unsigned short* CW0 = (unsigned short*)(ws + oCW0);  // c_whh0 split
        unsigned short* CW1 = (unsigned short*)(ws + oCW1);  // c_wih1
        unsigned short* CW2 = (unsigned short*)(ws + oCW2);  // c_whh1
        unsigned short* WZC = (unsigned short*)(ws + oWZC);
        unsigned short* NPW = (unsigned short*)(ws + oNPW);
        unsigned short* ZS  = (unsigned short*)(ws + oZS);
        unsigned short* CDW = (unsigned short*)(ws + oCDW);
        unsigned short* D0R = (unsigned short*)(ws + oD0R);  // d_wih0[:,128:]
        float* CG  = (float*)(ws + oCG);
        float* CC  = (float*)(ws + oCC);
        unsigned short* HC  = (unsigned short*)(ws + oHC);
        unsigned short* CND = (unsigned short*)(ws + oCND);
        unsigned short* PRV = (unsigned short*)(ws + oPRV);
        unsigned short* EMB = (unsigned short*)(ws + oEMB);
        float* BRP = (float*)(ws + oBRP);
        float* DG  = (float*)(ws + oDG);
        unsigned short* HD0 = (unsigned short*)(ws + oHD0);
        unsigned short* HD1 = (unsigned short*)(ws + oHD1);
        float* CD0 = (float*)(ws + oCD0);
        float* CD1 = (float*)(ws + oCD1);
        // decoder weights alias (converted after conductor finishes, stream-ordered)
        unsigned short* DWHH0 = CW0;
        unsigned short* DWIH1 = CW1;
        unsigned short* DWHH1 = CW2;
        unsigned short* D0E   = WZC;                                  // d_wih0[:, :128]
        unsigned short* OPW   = WZC + (size_t)2*4096*128;             // op_w split

        // split-pointer helpers: hi = p, lo = p + R*C
        auto split = [&](const float* src, int ldsrc, int c0, long R, long C, unsigned short* dst) {
            long total = R * C;
            split_pack<<<(unsigned)((total/4 + 255) / 256), 256, 0, stream>>>(
                src, ldsrc, c0, total, (int)C, dst, dst + total);
        };
        auto gemm = [&](int M, int N,
                        const unsigned short* A1, int K1, int lda1, const unsigned short* W1, int ldw1,
                        const unsigned short* A2, int K2, int lda2, const unsigned short* W2, int ldw2,
                        const float* Addp, int ldadd, const float* bb1, const float* bb2,
                        float* Cp, int ldc, unsigned short* Chi, unsigned short* Clo,
                        int mode, int ss) {
            const unsigned short* A1l = A1 ? A1 + (size_t)M*lda1 : nullptr;
            const unsigned short* W1l = W1 ? W1 + (size_t)N*ldw1 : nullptr;
            const unsigned short* A2l = A2 ? A2 + (size_t)M*lda2 : nullptr;
            const unsigned short* W2l = W2 ? W2 + (size_t)N*ldw2 : nullptr;
            dim3 grid(M / 64, N / 128);
            gemm_mfma<<<grid, 256, 0, stream>>>(M, N, A1, A1l, K1, lda1, W1, W1l, ldw1,
                                                A2, A2l, K2, lda2, W2, W2l, ldw2,
                                                Addp, ldadd, bb1, bb2, Cp, ldc, Chi, Clo, mode, ss);
        };
        // NOTE: the A-lo pointer convention above assumes lo = hi + M*lda. For
        // sliced A (emb per-step) we pass explicit pointers below via gemm2.
        auto gemm2 = [&](int M, int N,
                         const unsigned short* A1h, const unsigned short* A1l, int K1, int lda1,
                         const unsigned short* W1, int ldw1,
                         const unsigned short* A2h, const unsigned short* A2l, int K2, int lda2,
                         const unsigned short* W2, int ldw2,
                         const float* Addp, int ldadd, const float* bb1, const float* bb2,
                         float* Cp, int ldc, unsigned short* Chi, unsigned short* Clo,
                         int mode, int ss) {
            const unsigned short* W1l = W1 ? W1 + (size_t)N*ldw1 : nullptr;
            const unsigned short* W2l = W2 ? W2 + (size_t)N*ldw2 : nullptr;
            dim3 grid(M / 64, N / 128);
            gemm_mfma<<<grid, 256, 0, stream>>>(M, N, A1h, A1l, K1, lda1, W1, W1l, ldw1,
                                                A2h, A2l, K2, lda2, W2, W2l, ldw2,
                                                Addp, ldadd, bb1, bb2, Cp, ldc, Chi, Clo, mode, ss);
        };

        // 0) weight/state conversions needed before the conductor
        split(z, 512, 0, 64, 512, ZS);
        split(w_zc, 512, 0, 4096, 512, WZC);
        split(c_whh0, 1024, 0, 4096, 1024, CW0);
        split(c_wih1, 1024, 0, 4096, 1024, CW1);
        split(c_whh1, 1024, 0, 4096, 1024, CW2);
        split(np_w, 128, 0, 128, 128, NPW);
        split(cd_w, 1024, 0, 4096, 1024, CDW);
        split(d_wih0, 1152, 128, 4096, 1024, D0R);
        build_prev_b<<<8192, 256, 0, stream>>>(tp, PRV, PRV + 2097152);

        // 1) ini = z @ w_zc.T + b_zc -> CG -> split-scatter to conductor h/c
        gemm(64, 4096, ZS, 512, 512, WZC, 512, nullptr, 0, 0, nullptr, 0,
             nullptr, 0, b_zc, nullptr, CG, 4096, nullptr, nullptr, 0, -1);
        scatter_ini_split<<<512, 256, 0, stream>>>(CG, HC, HC + 131072, CC);

        // 2) emb = prev @ np_w.T + np_b  (split output)
        gemm2(16384, 128, PRV, PRV + 2097152, 128, 128, NPW, 128,
              nullptr, nullptr, 0, 0, nullptr, 0,
              nullptr, 0, np_b, nullptr, nullptr, 128, EMB, EMB + 2097152, 1, -1);

        // 3) conductor: 16 steps, 2 layers, batch 64 (layer-0 input is zeros)
        unsigned short* HC0h = HC;              unsigned short* HC0l = HC + 131072;
        unsigned short* HC1h = HC + 65536;      unsigned short* HC1l = HC + 131072 + 65536;
        for (int t = 0; t < 16; ++t) {
            gemm2(64, 4096, HC0h, HC0l, 1024, 1024, CW0, 1024,
                  nullptr, nullptr, 0, 0, nullptr, 0,
                  nullptr, 0, c_bih0, c_bhh0, CG, 4096, nullptr, nullptr, 0, -1);
            lstm_cell_split<<<256, 256, 0, stream>>>(CG, CC, HC0h, HC0l, nullptr, nullptr, 64);
            gemm2(64, 4096, HC0h, HC0l, 1024, 1024, CW1, 1024,
                  HC1h, HC1l, 1024, 1024, CW2, 1024,
                  nullptr, 0, c_bih1, c_bhh1, CG, 4096, nullptr, nullptr, 0, -1);
            lstm_cell_split<<<256, 256, 0, stream>>>(CG, CC + 65536, HC1h, HC1l,
                                                     CND + t * 65536, CND + 1048576 + t * 65536, 64);
        }

        // 4) convert decoder weights (aliases CW0..2/WZC -- safe: stream-ordered after conductor)
        split(d_whh0, 1024, 0, 4096, 1024, DWHH0);
        split(d_wih1, 1024, 0, 4096, 1024, DWIH1);
        split(d_whh1, 1024, 0, 4096, 1024, DWHH1);
        split(d_wih0, 1152, 0, 4096, 128, D0E);
        split(op_w, 1024, 0, 384, 1024, OPW);

        // 5) di = cond @ cd_w.T + cd_b -> DG -> split scatter
        gemm2(1024, 4096, CND, CND + 1048576, 1024, 1024, CDW, 1024,
              nullptr, nullptr, 0, 0, nullptr, 0,
              nullptr, 0, cd_b, nullptr, DG, 4096, nullptr, nullptr, 0, -1);
        scatter_di_split<<<4096, 256, 0, stream>>>(DG, HD0, HD0 + 1048576,
                                                   HD1, HD1 + 1048576, CD0, CD1);

        // 6) barpart = cond @ d_wih0[:,128:].T + bih0 + bhh0
        gemm2(1024, 4096, CND, CND + 1048576, 1024, 1024, D0R, 1024,
              nullptr, nullptr, 0, 0, nullptr, 0,
              nullptr, 0, d_bih0, d_bhh0, BRP, 4096, nullptr, nullptr, 0, -1);

        // 7) decoder: 16 steps, 2 layers, batch 1024
        for (int s = 0; s < 16; ++s) {
            gemm2(1024, 4096, EMB + (size_t)s * 131072, EMB + 2097152 + (size_t)s * 131072, 128, 128,
                  D0E, 128,
                  HD0, HD0 + 1048576, 1024, 1024, DWHH0, 1024,
                  BRP, 4096, nullptr, nullptr, DG, 4096, nullptr, nullptr, 0, -1);
            lstm_cell_split<<<4096, 256, 0, stream>>>(DG, CD0, HD0, HD0 + 1048576, nullptr, nullptr, 1024);
            gemm2(1024, 4096, HD0, HD0 + 1048576, 1024, 1024, DWIH1, 1024,
                  HD1, HD1 + 1048576, 1024, 1024, DWHH1, 1024,
                  nullptr, 0, d_bih1, d_bhh1, DG, 4096, nullptr, nullptr, 0, -1);
            lstm_cell_split<<<4096, 256, 0, stream>>>(DG, CD1, HD1, HD1 + 1048576, nullptr, nullptr, 1024);
            gemm2(1024, 384, HD1, HD1 + 1048576, 1024, 1024, OPW, 1024,
                  nullptr, nullptr, 0, 0, nullptr, 0,
                  nullptr, 0, op_b, nullptr, out, 384, nullptr, nullptr, 2, s);
        }
        return;
    }

    // ================= fallback: proven fp32 path =================
    float* wsf     = (float*)d_ws;
    float* hc      = wsf;
    float* cc      = hc + 131072;
    float* cond    = cc + 131072;
    float* cg      = cond + 1048576;
    float* barpart = cg + 262144;
    float* emb     = barpart + 4194304;
    float* prevf   = emb + 2097152;
    float* hd0     = prevf + 2097152;
    float* cd0     = hd0 + 1048576;
    float* hd1     = cd0 + 1048576;
    float* cd1     = hd1 + 1048576;
    float* dg      = cd1 + 1048576;

    auto gemmf = [&](int M, int N,
                     const float* A1, int K1, int lda1, const float* W1, int ldw1,
                     const float* A2, int K2, int lda2, const float* W2, int ldw2,
                     const float* Addp, int ldadd, const float* bb1, const float* bb2,
                     float* Cp, int ldc, int ss) {
        dim3 grid(M / BM, N / BN);
        gemm_f32<<<grid, dim3(256), 0, stream>>>(M, N, A1, K1, lda1, W1, ldw1,
                                                 A2, K2, lda2, W2, ldw2,
                                                 Addp, ldadd, bb1, bb2, Cp, ldc, ss);
    };

    gemmf(64, 4096, z, 512, 512, w_zc, 512, nullptr, 0, 0, nullptr, 0,
          nullptr, 0, b_zc, nullptr, cg, 4096, -1);
    scatter_ini<<<512, 256, 0, stream>>>(cg, hc, cc);

    build_prev<<<8192, 256, 0, stream>>>(tp, prevf);
    gemmf(16384, 128, prevf, 128, 128, np_w, 128, nullptr, 0, 0, nullptr, 0,
          nullptr, 0, np_b, nullptr, emb, 128, -1);

    for (int t = 0; t < 16; ++t) {
        gemmf(64, 4096, hc, 1024, 1024, c_whh0, 1024, nullptr, 0, 0, nullptr, 0,
              nullptr, 0, c_bih0, c_bhh0, cg, 4096, -1);
        lstm_cell<<<256, 256, 0, stream>>>(cg, cc, hc, nullptr, 64);
        gemmf(64, 4096, hc, 1024, 1024, c_wih1, 1024,
              hc + 65536, 1024, 1024, c_whh1, 1024,
              nullptr, 0, c_bih1, c_bhh1, cg, 4096, -1);
        lstm_cell<<<256, 256, 0, stream>>>(cg, cc + 65536, hc + 65536, cond + t * 65536, 64);
    }

    gemmf(1024, 4096, cond, 1024, 1024, cd_w, 1024, nullptr, 0, 0, nullptr, 0,
          nullptr, 0, cd_b, nullptr, dg, 4096, -1);
    scatter_di<<<4096, 256, 0, stream>>>(dg, hd0, cd0, hd1, cd1);

    gemmf(1024, 4096, cond, 1024, 1024, d_wih0 + 128, 1152, nullptr, 0, 0, nullptr, 0,
          nullptr, 0, d_bih0, d_bhh0, barpart, 4096, -1);

    for (int s = 0; s < 16; ++s) {
        gemmf(1024, 4096, emb + (size_t)s * 131072, 128, 128, d_wih0, 1152,
              hd0, 1024, 1024, d_whh0, 1024,
              barpart, 4096, nullptr, nullptr, dg, 4096, -1);
        lstm_cell<<<4096, 256, 0, stream>>>(dg, cd0, hd0, nullptr, 1024);
        gemmf(1024, 4096, hd0, 1024, 1024, d_wih1, 1024,
              hd1, 1024, 1024, d_whh1, 1024,
              nullptr, 0, d_bih1, d_bhh1, dg, 4096, -1);
        lstm_cell<<<4096, 256, 0, stream>>>(dg, cd1, hd1, nullptr, 1024);
        gemmf(1024, 384, hd1, 1024, 1024, op_w, 1024, nullptr, 0, 0, nullptr, 0,
              nullptr, 0, op_b, nullptr, out, 384, s);
    }
}

// Round 7
// 5253.636 us; speedup vs baseline: 2.0215x; 1.1440x over previous
//
#include <hip/hip_runtime.h>
#include <math.h>

// B=64, LAT=512, HC=HD=1024, NB=16, S=16, E=128, NOTES=128, OUT=384, L=2
// Split-bf16 MFMA GEMMs (x ~= hi+lo; A@W ~= Ah@Wh + Al@Wh + Ah@Wl).
// This round: double-buffered LDS pipeline + XCD-aware block swizzle.

typedef __attribute__((ext_vector_type(8))) short s16x8;
typedef __attribute__((ext_vector_type(4))) float f32x4;

__device__ inline unsigned short f2bu(float f) {   // RNE f32->bf16
    unsigned u = __float_as_uint(f);
    unsigned r = u + 0x7fff + ((u >> 16) & 1);
    return (unsigned short)(r >> 16);
}
__device__ inline float bu2f(unsigned short h) { return __uint_as_float(((unsigned)h) << 16); }

// ---------------------------------------------------------------------------
// MFMA GEMM: C[M][N] = A1@W1[:, :K1].T + A2@W2.T + Add + b1 + b2
// Tile 64x128, BK=32, 256 thr = 4 waves. LDS: double-buffered 2x(8KB A + 16KB W),
// XOR swizzle slot^=(row&7) on 16B slots -> conflict-free b128.
// Pipeline: load t+1 to regs || MFMA t || write LDS t+1 || 1 barrier/iter.
// mode: 0 = fp32 C; 1 = split store Chi/Clo; 2 = scatter to out (decoder perm).
__global__ __launch_bounds__(256) void gemm_mfma(
    int M, int N,
    const unsigned short* __restrict__ A1h, const unsigned short* __restrict__ A1l, int K1, int lda1,
    const unsigned short* __restrict__ W1h, const unsigned short* __restrict__ W1l, int ldw1,
    const unsigned short* __restrict__ A2h, const unsigned short* __restrict__ A2l, int K2, int lda2,
    const unsigned short* __restrict__ W2h, const unsigned short* __restrict__ W2l, int ldw2,
    const float* __restrict__ Add, int ldadd,
    const float* __restrict__ b1, const float* __restrict__ b2,
    float* __restrict__ C, int ldc,
    unsigned short* __restrict__ Chi, unsigned short* __restrict__ Clo,
    int mode, int scatter_s)
{
    __shared__ __align__(16) char ldsb[49152];   // 2 buffers x 24576 B

    const int tid = threadIdx.x;
    const int lane = tid & 63;
    const int wv = tid >> 6;

    // XCD-aware bijective swizzle (all our grids have nwg % 8 == 0):
    // dispatch-linear l -> chunk l2 so each XCD owns a contiguous run of
    // N-panels (W reuse in its private L2).
    const int gx = gridDim.x;
    const int l = blockIdx.y * gx + blockIdx.x;
    const int nwg = gx * gridDim.y;
    const int l2 = (l & 7) * (nwg >> 3) + (l >> 3);
    const int bm = (l2 % gx) * 64;
    const int bn = (l2 / gx) * 128;

    // staging assignments (constant per thread)
    const int rowA = tid >> 2;              // 0..63
    const int hA = (tid & 3) * 2;           // slots hA, hA+1 (never straddles hi/lo)
    const bool aIsLo = hA >= 4;
    const int koffA = (hA & 3) * 8;
    const int swA = (rowA & 7) << 4;
    const int ldsA0 = rowA * 128 + ((hA * 16) ^ swA);
    const int ldsA1 = rowA * 128 + (((hA + 1) * 16) ^ swA);

    const int rowB = tid >> 1;              // 0..127
    const bool bIsLo = (tid & 1) != 0;
    const int swB = (rowB & 7) << 4;
    const int sB = bIsLo ? 4 : 0;
    const int ldsB0 = 8192 + rowB * 128 + (((sB + 0) * 16) ^ swB);
    const int ldsB1 = 8192 + rowB * 128 + (((sB + 1) * 16) ^ swB);
    const int ldsB2 = 8192 + rowB * 128 + (((sB + 2) * 16) ^ swB);
    const int ldsB3 = 8192 + rowB * 128 + (((sB + 3) * 16) ^ swB);

    f32x4 acc[4][2];
#pragma unroll
    for (int m = 0; m < 4; ++m)
#pragma unroll
        for (int n = 0; n < 2; ++n) acc[m][n] = (f32x4)0.0f;

    const int fr = lane & 15;               // frag row/col
    const int kc = lane >> 4;               // k-chunk 0..3

    const int NT = (K1 + K2) >> 5;
    s16x8 va0, va1, vb0, vb1, vb2, vb3;     // in-flight staging registers

#define LOADT(t) {                                                              \
        const int k0 = (t) << 5;                                                \
        const bool ph2 = (k0 >= K1);                                            \
        const unsigned short* Ah_ = ph2 ? A2h : A1h;                            \
        const unsigned short* Al_ = ph2 ? A2l : A1l;                            \
        const unsigned short* Wh_ = ph2 ? W2h : W1h;                            \
        const unsigned short* Wl_ = ph2 ? W2l : W1l;                            \
        const int lda_ = ph2 ? lda2 : lda1;                                     \
        const int ldw_ = ph2 ? ldw2 : ldw1;                                     \
        const int kk_ = ph2 ? (k0 - K1) : k0;                                   \
        const unsigned short* ap = (aIsLo ? Al_ : Ah_)                          \
            + (size_t)(bm + rowA) * lda_ + kk_ + koffA;                         \
        va0 = *(const s16x8*)(ap);                                              \
        va1 = *(const s16x8*)(ap + 8);                                          \
        const unsigned short* bp = (bIsLo ? Wl_ : Wh_)                          \
            + (size_t)(bn + rowB) * ldw_ + kk_;                                 \
        vb0 = *(const s16x8*)(bp);                                              \
        vb1 = *(const s16x8*)(bp + 8);                                          \
        vb2 = *(const s16x8*)(bp + 16);                                         \
        vb3 = *(const s16x8*)(bp + 24);                                         \
    }

#define WRITET(buf) {                                                           \
        char* bb_ = ldsb + (buf) * 24576;                                       \
        *(s16x8*)(bb_ + ldsA0) = va0;                                           \
        *(s16x8*)(bb_ + ldsA1) = va1;                                           \
        *(s16x8*)(bb_ + ldsB0) = vb0;                                           \
        *(s16x8*)(bb_ + ldsB1) = vb1;                                           \
        *(s16x8*)(bb_ + ldsB2) = vb2;                                           \
        *(s16x8*)(bb_ + ldsB3) = vb3;                                           \
    }

    // prologue: tile 0 staged, visible to all
    LOADT(0);
    WRITET(0);
    __syncthreads();

    for (int t = 0; t < NT; ++t) {
        if (t + 1 < NT) LOADT(t + 1);       // loads in flight under MFMAs
        {
            char* bufb = ldsb + (t & 1) * 24576;
            s16x8 ah[4], al[4], bh[2], bl[2];
#pragma unroll
            for (int m = 0; m < 4; ++m) {
                const int row = m * 16 + fr;
                const int sw = (row & 7) << 4;
                char* base = bufb + row * 128;
                ah[m] = *(const s16x8*)(base + ((kc * 16) ^ sw));
                al[m] = *(const s16x8*)(base + (((kc + 4) * 16) ^ sw));
            }
#pragma unroll
            for (int n = 0; n < 2; ++n) {
                const int row = wv * 32 + n * 16 + fr;
                const int sw = (row & 7) << 4;
                char* base = bufb + 8192 + row * 128;
                bh[n] = *(const s16x8*)(base + ((kc * 16) ^ sw));
                bl[n] = *(const s16x8*)(base + (((kc + 4) * 16) ^ sw));
            }
#pragma unroll
            for (int m = 0; m < 4; ++m)
#pragma unroll
                for (int n = 0; n < 2; ++n) {
                    acc[m][n] = __builtin_amdgcn_mfma_f32_16x16x32_bf16(ah[m], bh[n], acc[m][n], 0, 0, 0);
                    acc[m][n] = __builtin_amdgcn_mfma_f32_16x16x32_bf16(al[m], bh[n], acc[m][n], 0, 0, 0);
                    acc[m][n] = __builtin_amdgcn_mfma_f32_16x16x32_bf16(ah[m], bl[n], acc[m][n], 0, 0, 0);
                }
        }
        if (t + 1 < NT) WRITET((t + 1) & 1);  // writes buffer computed at t-1 (barrier-safe)
        __syncthreads();
    }
#undef LOADT
#undef WRITET

    // epilogue: C/D layout col=lane&15, row=(lane>>4)*4+reg
#pragma unroll
    for (int m = 0; m < 4; ++m)
#pragma unroll
        for (int n = 0; n < 2; ++n) {
            f32x4 v4 = acc[m][n];
#pragma unroll
            for (int q = 0; q < 4; ++q) {
                const int rl = m * 16 + kc * 4 + q;
                const int cl = wv * 32 + n * 16 + fr;
                const int r = bm + rl, col = bn + cl;
                float v = v4[q];
                if (b1) v += b1[col];
                if (b2) v += b2[col];
                if (Add) v += Add[(size_t)r * ldadd + col];
                if (mode == 0) {
                    C[(size_t)r * ldc + col] = v;
                } else if (mode == 1) {
                    unsigned short h = f2bu(v);
                    Chi[(size_t)r * ldc + col] = h;
                    Clo[(size_t)r * ldc + col] = f2bu(v - bu2f(h));
                } else {
                    const int bb = r & 63, nb = r >> 6;
                    C[(size_t)(((bb * 16 + nb) * 16 + scatter_s)) * 384 + col] = v;
                }
            }
        }
}

// ---------------------------------------------------------------------------
// split fp32 -> (hi,lo) bf16. src strided [R][ldsrc], take C cols from c0.
__global__ __launch_bounds__(256) void split_pack(
    const float* __restrict__ src, int ldsrc, int c0, long total, int C,
    unsigned short* __restrict__ hi, unsigned short* __restrict__ lo)
{
    long i = ((long)blockIdx.x * 256 + threadIdx.x) * 4;
    if (i >= total) return;
    int r = (int)(i / C), c = (int)(i % C);
    float4 v = *(const float4*)(src + (size_t)r * ldsrc + c0 + c);
#pragma unroll
    for (int j = 0; j < 4; ++j) {
        float x = (&v.x)[j];
        unsigned short h = f2bu(x);
        hi[i + j] = h;
        lo[i + j] = f2bu(x - bu2f(h));
    }
}

// LSTM pointwise with split-bf16 h output (+ optional copy)
__global__ __launch_bounds__(256) void lstm_cell_split(
    const float* __restrict__ g, float* __restrict__ c,
    unsigned short* __restrict__ hhi, unsigned short* __restrict__ hlo,
    unsigned short* __restrict__ cpyh, unsigned short* __restrict__ cpyl, int M)
{
    const int idx = blockIdx.x * blockDim.x + threadIdx.x;
    if (idx >= (M << 10)) return;
    const int r = idx >> 10, k = idx & 1023;
    const float* gr = g + ((size_t)r << 12);
    const float gi = gr[k], gf = gr[k + 1024], gg = gr[k + 2048], go = gr[k + 3072];
    const float si = 1.f / (1.f + expf(-gi));
    const float sf = 1.f / (1.f + expf(-gf));
    const float so = 1.f / (1.f + expf(-go));
    const float cn = sf * c[idx] + si * tanhf(gg);
    const float hn = so * tanhf(cn);
    c[idx] = cn;
    unsigned short h = f2bu(hn);
    unsigned short l = f2bu(hn - bu2f(h));
    hhi[idx] = h; hlo[idx] = l;
    if (cpyh) { cpyh[idx] = h; cpyl[idx] = l; }
}

// ini [64][4096] -> hc split [2][64][1024], cc fp32
__global__ __launch_bounds__(256) void scatter_ini_split(
    const float* __restrict__ I, unsigned short* __restrict__ hchi,
    unsigned short* __restrict__ hclo, float* __restrict__ cc)
{
    const int idx = blockIdx.x * blockDim.x + threadIdx.x;
    if (idx >= 131072) return;
    const int k = idx & 1023, b = (idx >> 10) & 63, l = idx >> 16;
    const float* row = I + (size_t)b * 4096;
    float hv = row[(l << 10) + k];
    unsigned short h = f2bu(hv);
    hchi[idx] = h; hclo[idx] = f2bu(hv - bu2f(h));
    cc[idx] = row[2048 + (l << 10) + k];
}

// di [1024][4096] -> hd0/hd1 split, cd0/cd1 fp32
__global__ __launch_bounds__(256) void scatter_di_split(
    const float* __restrict__ D,
    unsigned short* __restrict__ h0h, unsigned short* __restrict__ h0l,
    unsigned short* __restrict__ h1h, unsigned short* __restrict__ h1l,
    float* __restrict__ cd0, float* __restrict__ cd1)
{
    const int idx = blockIdx.x * blockDim.x + threadIdx.x;
    if (idx >= 1048576) return;
    const int k = idx & 1023, r = idx >> 10;
    const float* row = D + ((size_t)r << 12);
    float v0 = row[k], v1 = row[1024 + k];
    unsigned short a = f2bu(v0); h0h[idx] = a; h0l[idx] = f2bu(v0 - bu2f(a));
    unsigned short b = f2bu(v1); h1h[idx] = b; h1l[idx] = f2bu(v1 - bu2f(b));
    cd0[idx] = row[2048 + k];
    cd1[idx] = row[3072 + k];
}

// prev (teacher-forced, integer 0..2 -> exact bf16, lo = 0)
__global__ __launch_bounds__(256) void build_prev_b(
    const int* __restrict__ tp, unsigned short* __restrict__ ph, unsigned short* __restrict__ pl)
{
    const int idx = blockIdx.x * blockDim.x + threadIdx.x;
    if (idx >= 2097152) return;
    const int n = idx & 127;
    const int r = (idx >> 7) & 1023;
    const int s = idx >> 17;
    const int nb = r >> 6, bb = r & 63;
    const int t = nb * 16 + s;
    float v = 0.f;
    if (t > 0) v = (float)tp[(size_t)bb * 32768 + (size_t)(t - 1) * 128 + n];
    ph[idx] = f2bu(v);
    pl[idx] = 0;
}

// ===========================================================================
// Fallback fp32 path (proven baseline)
#define BM 64
#define BN 64
#define BK 16

__global__ __launch_bounds__(256) void gemm_f32(
    int M, int N,
    const float* __restrict__ A1, int K1, int lda1,
    const float* __restrict__ W1, int ldw1,
    const float* __restrict__ A2, int K2, int lda2,
    const float* __restrict__ W2, int ldw2,
    const float* __restrict__ Add, int ldadd,
    const float* __restrict__ bias1, const float* __restrict__ bias2,
    float* __restrict__ C, int ldc, int scatter_s)
{
    __shared__ float As[BK][BM];
    __shared__ float Ws[BK][BN];
    const int bm = blockIdx.x * BM;
    const int bn = blockIdx.y * BN;
    const int tid = threadIdx.x;
    const int ty = tid >> 4;
    const int tx = tid & 15;
    const int lr = tid >> 2;
    const int lc = (tid & 3) << 2;

    float acc[4][4] = {{0.f,0.f,0.f,0.f},{0.f,0.f,0.f,0.f},{0.f,0.f,0.f,0.f},{0.f,0.f,0.f,0.f}};

    for (int phase = 0; phase < 2; ++phase) {
        const float* Ap = phase ? A2 : A1;
        const float* Wp = phase ? W2 : W1;
        const int K   = phase ? K2 : K1;
        const int lda = phase ? lda2 : lda1;
        const int ldw = phase ? ldw2 : ldw1;
        if (Ap == nullptr || K <= 0) continue;
        for (int k0 = 0; k0 < K; k0 += BK) {
            float4 av = *(const float4*)(Ap + (size_t)(bm + lr) * lda + k0 + lc);
            float4 wv = *(const float4*)(Wp + (size_t)(bn + lr) * ldw + k0 + lc);
            __syncthreads();
            As[lc+0][lr] = av.x; As[lc+1][lr] = av.y; As[lc+2][lr] = av.z; As[lc+3][lr] = av.w;
            Ws[lc+0][lr] = wv.x; Ws[lc+1][lr] = wv.y; Ws[lc+2][lr] = wv.z; Ws[lc+3][lr] = wv.w;
            __syncthreads();
            #pragma unroll
            for (int k = 0; k < BK; ++k) {
                float4 a = *(const float4*)&As[k][ty << 2];
                float4 w = *(const float4*)&Ws[k][tx << 2];
                acc[0][0] = fmaf(a.x, w.x, acc[0][0]);
                acc[0][1] = fmaf(a.x, w.y, acc[0][1]);
                acc[0][2] = fmaf(a.x, w.z, acc[0][2]);
                acc[0][3] = fmaf(a.x, w.w, acc[0][3]);
                acc[1][0] = fmaf(a.y, w.x, acc[1][0]);
                acc[1][1] = fmaf(a.y, w.y, acc[1][1]);
                acc[1][2] = fmaf(a.y, w.z, acc[1][2]);
                acc[1][3] = fmaf(a.y, w.w, acc[1][3]);
                acc[2][0] = fmaf(a.z, w.x, acc[2][0]);
                acc[2][1] = fmaf(a.z, w.y, acc[2][1]);
                acc[2][2] = fmaf(a.z, w.z, acc[2][2]);
                acc[2][3] = fmaf(a.z, w.w, acc[2][3]);
                acc[3][0] = fmaf(a.w, w.x, acc[3][0]);
                acc[3][1] = fmaf(a.w, w.y, acc[3][1]);
                acc[3][2] = fmaf(a.w, w.z, acc[3][2]);
                acc[3][3] = fmaf(a.w, w.w, acc[3][3]);
            }
        }
    }

    #pragma unroll
    for (int i = 0; i < 4; ++i) {
        const int row = bm + (ty << 2) + i;
        #pragma unroll
        for (int j = 0; j < 4; ++j) {
            const int col = bn + (tx << 2) + j;
            float v = acc[i][j];
            if (bias1) v += bias1[col];
            if (bias2) v += bias2[col];
            if (Add)   v += Add[(size_t)row * ldadd + col];
            if (scatter_s >= 0) {
                const int bb = row & 63, nb = row >> 6;
                C[(size_t)(((bb * 16 + nb) * 16 + scatter_s)) * 384 + col] = v;
            } else {
                C[(size_t)row * ldc + col] = v;
            }
        }
    }
}

__global__ __launch_bounds__(256) void lstm_cell(
    const float* __restrict__ g, float* __restrict__ c,
    float* __restrict__ h, float* __restrict__ hcopy, int M)
{
    const int idx = blockIdx.x * blockDim.x + threadIdx.x;
    if (idx >= (M << 10)) return;
    const int r = idx >> 10, k = idx & 1023;
    const float* gr = g + ((size_t)r << 12);
    const float gi = gr[k], gf = gr[k + 1024], gg = gr[k + 2048], go = gr[k + 3072];
    const float si = 1.f / (1.f + expf(-gi));
    const float sf = 1.f / (1.f + expf(-gf));
    const float so = 1.f / (1.f + expf(-go));
    const float cn = sf * c[idx] + si * tanhf(gg);
    const float hn = so * tanhf(cn);
    c[idx] = cn;
    h[idx] = hn;
    if (hcopy) hcopy[idx] = hn;
}

__global__ __launch_bounds__(256) void scatter_ini(
    const float* __restrict__ I, float* __restrict__ hc, float* __restrict__ cc)
{
    const int idx = blockIdx.x * blockDim.x + threadIdx.x;
    if (idx >= 131072) return;
    const int k = idx & 1023, b = (idx >> 10) & 63, l = idx >> 16;
    const float* row = I + (size_t)b * 4096;
    hc[idx] = row[(l << 10) + k];
    cc[idx] = row[2048 + (l << 10) + k];
}

__global__ __launch_bounds__(256) void scatter_di(
    const float* __restrict__ D, float* __restrict__ hd0, float* __restrict__ cd0,
    float* __restrict__ hd1, float* __restrict__ cd1)
{
    const int idx = blockIdx.x * blockDim.x + threadIdx.x;
    if (idx >= 1048576) return;
    const int k = idx & 1023, r = idx >> 10;
    const float* row = D + ((size_t)r << 12);
    hd0[idx] = row[k];
    hd1[idx] = row[1024 + k];
    cd0[idx] = row[2048 + k];
    cd1[idx] = row[3072 + k];
}

__global__ __launch_bounds__(256) void build_prev(
    const int* __restrict__ tp, float* __restrict__ prevf)
{
    const int idx = blockIdx.x * blockDim.x + threadIdx.x;
    if (idx >= 2097152) return;
    const int n = idx & 127;
    const int r = (idx >> 7) & 1023;
    const int s = idx >> 17;
    const int nb = r >> 6, bb = r & 63;
    const int t = nb * 16 + s;
    float v = 0.f;
    if (t > 0) v = (float)tp[(size_t)bb * 32768 + (size_t)(t - 1) * 128 + n];
    prevf[idx] = v;
}

// ===========================================================================
extern "C" void kernel_launch(void* const* d_in, const int* in_sizes, int n_in,
                              void* d_out, int out_size, void* d_ws, size_t ws_size,
                              hipStream_t stream)
{
    (void)in_sizes; (void)n_in; (void)out_size;
    const float* z      = (const float*)d_in[0];
    const int*   tp     = (const int*)  d_in[1];
    const float* w_zc   = (const float*)d_in[2];
    const float* b_zc   = (const float*)d_in[3];
    const float* c_whh0 = (const float*)d_in[5];
    const float* c_bih0 = (const float*)d_in[6];
    const float* c_bhh0 = (const float*)d_in[7];
    const float* c_wih1 = (const float*)d_in[8];
    const float* c_whh1 = (const float*)d_in[9];
    const float* c_bih1 = (const float*)d_in[10];
    const float* c_bhh1 = (const float*)d_in[11];
    const float* np_w   = (const float*)d_in[12];
    const float* np_b   = (const float*)d_in[13];
    const float* cd_w   = (const float*)d_in[14];
    const float* cd_b   = (const float*)d_in[15];
    const float* d_wih0 = (const float*)d_in[16];
    const float* d_whh0 = (const float*)d_in[17];
    const float* d_bih0 = (const float*)d_in[18];
    const float* d_bhh0 = (const float*)d_in[19];
    const float* d_wih1 = (const float*)d_in[20];
    const float* d_whh1 = (const float*)d_in[21];
    const float* d_bih1 = (const float*)d_in[22];
    const float* d_bhh1 = (const float*)d_in[23];
    const float* op_w   = (const float*)d_in[24];
    const float* op_b   = (const float*)d_in[25];
    float* out = (float*)d_out;

    // ---- workspace layout for MFMA path (bytes) ----
    size_t o = 0;
    auto alloc = [&](size_t bytes) { size_t r = o; o = (o + bytes + 255) & ~(size_t)255; return r; };
    const size_t oCW0 = alloc((size_t)4096*1024*4);   // split buffers: 2*R*C ushorts = R*C*4 B
    const size_t oCW1 = alloc((size_t)4096*1024*4);
    const size_t oCW2 = alloc((size_t)4096*1024*4);
    const size_t oWZC = alloc((size_t)4096*512*4);    // later re-used for DWIH0E + OPW
    const size_t oNPW = alloc((size_t)128*128*4);
    const size_t oZS  = alloc((size_t)64*512*4);
    const size_t oCDW = alloc((size_t)4096*1024*4);
    const size_t oD0R = alloc((size_t)4096*1024*4);
    const size_t oCG  = alloc((size_t)64*4096*4);
    const size_t oCC  = alloc((size_t)2*64*1024*4);
    const size_t oHC  = alloc((size_t)2*64*1024*4);   // split
    const size_t oCND = alloc((size_t)1024*1024*4);   // split
    const size_t oPRV = alloc((size_t)16*1024*128*4); // split (lo = 0)
    const size_t oEMB = alloc((size_t)16*1024*128*4); // split
    const size_t oBRP = alloc((size_t)1024*4096*4);
    const size_t oDG  = alloc((size_t)1024*4096*4);
    const size_t oHD0 = alloc((size_t)1024*1024*4);   // split
    const size_t oHD1 = alloc((size_t)1024*1024*4);   // split
    const size_t oCD0 = alloc((size_t)1024*1024*4);
    const size_t oCD1 = alloc((size_t)1024*1024*4);
    const size_t need = o;

    if (ws_size >= need) {
        // ================= MFMA split-bf16 path =================
        char* ws = (char*)d_ws;
        unsigned short* CW0 = (unsigned short*)(ws + oCW0);  // c_whh0 split
        unsigned short* CW1 = (unsigned short*)(ws + oCW1);  // c_wih1
        unsigned short* CW2 = (unsigned short*)(ws + oCW2);  // c_whh1
        unsigned short* WZC = (unsigned short*)(ws + oWZC);
        unsigned short* NPW = (unsigned short*)(ws + oNPW);
        unsigned short* ZS  = (unsigned short*)(ws + oZS);
        unsigned short* CDW = (unsigned short*)(ws + oCDW);
        unsigned short* D0R = (unsigned short*)(ws + oD0R);  // d_wih0[:,128:]
        float* CG  = (float*)(ws + oCG);
        float* CC  = (float*)(ws + oCC);
        unsigned short* HC  = (unsigned short*)(ws + oHC);
        unsigned short* CND = (unsigned short*)(ws + oCND);
        unsigned short* PRV = (unsigned short*)(ws + oPRV);
        unsigned short* EMB = (unsigned short*)(ws + oEMB);
        float* BRP = (float*)(ws + oBRP);
        float* DG  = (float*)(ws + oDG);
        unsigned short* HD0 = (unsigned short*)(ws + oHD0);
        unsigned short* HD1 = (unsigned short*)(ws + oHD1);
        float* CD0 = (float*)(ws + oCD0);
        float* CD1 = (float*)(ws + oCD1);
        // decoder weights alias (converted after conductor finishes, stream-ordered)
        unsigned short* DWHH0 = CW0;
        unsigned short* DWIH1 = CW1;
        unsigned short* DWHH1 = CW2;
        unsigned short* D0E   = WZC;                                  // d_wih0[:, :128]
        unsigned short* OPW   = WZC + (size_t)2*4096*128;             // op_w split

        // split-pointer helpers: hi = p, lo = p + R*C
        auto split = [&](const float* src, int ldsrc, int c0, long R, long C, unsigned short* dst) {
            long total = R * C;
            split_pack<<<(unsigned)((total/4 + 255) / 256), 256, 0, stream>>>(
                src, ldsrc, c0, total, (int)C, dst, dst + total);
        };
        auto gemm = [&](int M, int N,
                        const unsigned short* A1, int K1, int lda1, const unsigned short* W1, int ldw1,
                        const unsigned short* A2, int K2, int lda2, const unsigned short* W2, int ldw2,
                        const float* Addp, int ldadd, const float* bb1, const float* bb2,
                        float* Cp, int ldc, unsigned short* Chi, unsigned short* Clo,
                        int mode, int ss) {
            const unsigned short* A1l = A1 ? A1 + (size_t)M*lda1 : nullptr;
            const unsigned short* W1l = W1 ? W1 + (size_t)N*ldw1 : nullptr;
            const unsigned short* A2l = A2 ? A2 + (size_t)M*lda2 : nullptr;
            const unsigned short* W2l = W2 ? W2 + (size_t)N*ldw2 : nullptr;
            dim3 grid(M / 64, N / 128);
            gemm_mfma<<<grid, 256, 0, stream>>>(M, N, A1, A1l, K1, lda1, W1, W1l, ldw1,
                                                A2, A2l, K2, lda2, W2, W2l, ldw2,
                                                Addp, ldadd, bb1, bb2, Cp, ldc, Chi, Clo, mode, ss);
        };
        auto gemm2 = [&](int M, int N,
                         const unsigned short* A1h, const unsigned short* A1l, int K1, int lda1,
                         const unsigned short* W1, int ldw1,
                         const unsigned short* A2h, const unsigned short* A2l, int K2, int lda2,
                         const unsigned short* W2, int ldw2,
                         const float* Addp, int ldadd, const float* bb1, const float* bb2,
                         float* Cp, int ldc, unsigned short* Chi, unsigned short* Clo,
                         int mode, int ss) {
            const unsigned short* W1l = W1 ? W1 + (size_t)N*ldw1 : nullptr;
            const unsigned short* W2l = W2 ? W2 + (size_t)N*ldw2 : nullptr;
            dim3 grid(M / 64, N / 128);
            gemm_mfma<<<grid, 256, 0, stream>>>(M, N, A1h, A1l, K1, lda1, W1, W1l, ldw1,
                                                A2h, A2l, K2, lda2, W2, W2l, ldw2,
                                                Addp, ldadd, bb1, bb2, Cp, ldc, Chi, Clo, mode, ss);
        };

        // 0) weight/state conversions needed before the conductor
        split(z, 512, 0, 64, 512, ZS);
        split(w_zc, 512, 0, 4096, 512, WZC);
        split(c_whh0, 1024, 0, 4096, 1024, CW0);
        split(c_wih1, 1024, 0, 4096, 1024, CW1);
        split(c_whh1, 1024, 0, 4096, 1024, CW2);
        split(np_w, 128, 0, 128, 128, NPW);
        split(cd_w, 1024, 0, 4096, 1024, CDW);
        split(d_wih0, 1152, 128, 4096, 1024, D0R);
        build_prev_b<<<8192, 256, 0, stream>>>(tp, PRV, PRV + 2097152);

        // 1) ini = z @ w_zc.T + b_zc -> CG -> split-scatter to conductor h/c
        gemm(64, 4096, ZS, 512, 512, WZC, 512, nullptr, 0, 0, nullptr, 0,
             nullptr, 0, b_zc, nullptr, CG, 4096, nullptr, nullptr, 0, -1);
        scatter_ini_split<<<512, 256, 0, stream>>>(CG, HC, HC + 131072, CC);

        // 2) emb = prev @ np_w.T + np_b  (split output)
        gemm2(16384, 128, PRV, PRV + 2097152, 128, 128, NPW, 128,
              nullptr, nullptr, 0, 0, nullptr, 0,
              nullptr, 0, np_b, nullptr, nullptr, 128, EMB, EMB + 2097152, 1, -1);

        // 3) conductor: 16 steps, 2 layers, batch 64 (layer-0 input is zeros)
        unsigned short* HC0h = HC;              unsigned short* HC0l = HC + 131072;
        unsigned short* HC1h = HC + 65536;      unsigned short* HC1l = HC + 131072 + 65536;
        for (int t = 0; t < 16; ++t) {
            gemm2(64, 4096, HC0h, HC0l, 1024, 1024, CW0, 1024,
                  nullptr, nullptr, 0, 0, nullptr, 0,
                  nullptr, 0, c_bih0, c_bhh0, CG, 4096, nullptr, nullptr, 0, -1);
            lstm_cell_split<<<256, 256, 0, stream>>>(CG, CC, HC0h, HC0l, nullptr, nullptr, 64);
            gemm2(64, 4096, HC0h, HC0l, 1024, 1024, CW1, 1024,
                  HC1h, HC1l, 1024, 1024, CW2, 1024,
                  nullptr, 0, c_bih1, c_bhh1, CG, 4096, nullptr, nullptr, 0, -1);
            lstm_cell_split<<<256, 256, 0, stream>>>(CG, CC + 65536, HC1h, HC1l,
                                                     CND + t * 65536, CND + 1048576 + t * 65536, 64);
        }

        // 4) convert decoder weights (aliases CW0..2/WZC -- safe: stream-ordered after conductor)
        split(d_whh0, 1024, 0, 4096, 1024, DWHH0);
        split(d_wih1, 1024, 0, 4096, 1024, DWIH1);
        split(d_whh1, 1024, 0, 4096, 1024, DWHH1);
        split(d_wih0, 1152, 0, 4096, 128, D0E);
        split(op_w, 1024, 0, 384, 1024, OPW);

        // 5) di = cond @ cd_w.T + cd_b -> DG -> split scatter
        gemm2(1024, 4096, CND, CND + 1048576, 1024, 1024, CDW, 1024,
              nullptr, nullptr, 0, 0, nullptr, 0,
              nullptr, 0, cd_b, nullptr, DG, 4096, nullptr, nullptr, 0, -1);
        scatter_di_split<<<4096, 256, 0, stream>>>(DG, HD0, HD0 + 1048576,
                                                   HD1, HD1 + 1048576, CD0, CD1);

        // 6) barpart = cond @ d_wih0[:,128:].T + bih0 + bhh0
        gemm2(1024, 4096, CND, CND + 1048576, 1024, 1024, D0R, 1024,
              nullptr, nullptr, 0, 0, nullptr, 0,
              nullptr, 0, d_bih0, d_bhh0, BRP, 4096, nullptr, nullptr, 0, -1);

        // 7) decoder: 16 steps, 2 layers, batch 1024
        for (int s = 0; s < 16; ++s) {
            gemm2(1024, 4096, EMB + (size_t)s * 131072, EMB + 2097152 + (size_t)s * 131072, 128, 128,
                  D0E, 128,
                  HD0, HD0 + 1048576, 1024, 1024, DWHH0, 1024,
                  BRP, 4096, nullptr, nullptr, DG, 4096, nullptr, nullptr, 0, -1);
            lstm_cell_split<<<4096, 256, 0, stream>>>(DG, CD0, HD0, HD0 + 1048576, nullptr, nullptr, 1024);
            gemm2(1024, 4096, HD0, HD0 + 1048576, 1024, 1024, DWIH1, 1024,
                  HD1, HD1 + 1048576, 1024, 1024, DWHH1, 1024,
                  nullptr, 0, d_bih1, d_bhh1, DG, 4096, nullptr, nullptr, 0, -1);
            lstm_cell_split<<<4096, 256, 0, stream>>>(DG, CD1, HD1, HD1 + 1048576, nullptr, nullptr, 1024);
            gemm2(1024, 384, HD1, HD1 + 1048576, 1024, 1024, OPW, 1024,
                  nullptr, nullptr, 0, 0, nullptr, 0,
                  nullptr, 0, op_b, nullptr, out, 384, nullptr, nullptr, 2, s);
        }
        return;
    }

    // ================= fallback: proven fp32 path =================
    float* wsf     = (float*)d_ws;
    float* hc      = wsf;
    float* cc      = hc + 131072;
    float* cond    = cc + 131072;
    float* cg      = cond + 1048576;
    float* barpart = cg + 262144;
    float* emb     = barpart + 4194304;
    float* prevf   = emb + 2097152;
    float* hd0     = prevf + 2097152;
    float* cd0     = hd0 + 1048576;
    float* hd1     = cd0 + 1048576;
    float* cd1     = hd1 + 1048576;
    float* dg      = cd1 + 1048576;

    auto gemmf = [&](int M, int N,
                     const float* A1, int K1, int lda1, const float* W1, int ldw1,
                     const float* A2, int K2, int lda2, const float* W2, int ldw2,
                     const float* Addp, int ldadd, const float* bb1, const float* bb2,
                     float* Cp, int ldc, int ss) {
        dim3 grid(M / BM, N / BN);
        gemm_f32<<<grid, dim3(256), 0, stream>>>(M, N, A1, K1, lda1, W1, ldw1,
                                                 A2, K2, lda2, W2, ldw2,
                                                 Addp, ldadd, bb1, bb2, Cp, ldc, ss);
    };

    gemmf(64, 4096, z, 512, 512, w_zc, 512, nullptr, 0, 0, nullptr, 0,
          nullptr, 0, b_zc, nullptr, cg, 4096, -1);
    scatter_ini<<<512, 256, 0, stream>>>(cg, hc, cc);

    build_prev<<<8192, 256, 0, stream>>>(tp, prevf);
    gemmf(16384, 128, prevf, 128, 128, np_w, 128, nullptr, 0, 0, nullptr, 0,
          nullptr, 0, np_b, nullptr, emb, 128, -1);

    for (int t = 0; t < 16; ++t) {
        gemmf(64, 4096, hc, 1024, 1024, c_whh0, 1024, nullptr, 0, 0, nullptr, 0,
              nullptr, 0, c_bih0, c_bhh0, cg, 4096, -1);
        lstm_cell<<<256, 256, 0, stream>>>(cg, cc, hc, nullptr, 64);
        gemmf(64, 4096, hc, 1024, 1024, c_wih1, 1024,
              hc + 65536, 1024, 1024, c_whh1, 1024,
              nullptr, 0, c_bih1, c_bhh1, cg, 4096, -1);
        lstm_cell<<<256, 256, 0, stream>>>(cg, cc + 65536, hc + 65536, cond + t * 65536, 64);
    }

    gemmf(1024, 4096, cond, 1024, 1024, cd_w, 1024, nullptr, 0, 0, nullptr, 0,
          nullptr, 0, cd_b, nullptr, dg, 4096, -1);
    scatter_di<<<4096, 256, 0, stream>>>(dg, hd0, cd0, hd1, cd1);

    gemmf(1024, 4096, cond, 1024, 1024, d_wih0 + 128, 1152, nullptr, 0, 0, nullptr, 0,
          nullptr, 0, d_bih0, d_bhh0, barpart, 4096, -1);

    for (int s = 0; s < 16; ++s) {
        gemmf(1024, 4096, emb + (size_t)s * 131072, 128, 128, d_wih0, 1152,
              hd0, 1024, 1024, d_whh0, 1024,
              barpart, 4096, nullptr, nullptr, dg, 4096, -1);
        lstm_cell<<<4096, 256, 0, stream>>>(dg, cd0, hd0, nullptr, 1024);
        gemmf(1024, 4096, hd0, 1024, 1024, d_wih1, 1024,
              hd1, 1024, 1024, d_whh1, 1024,
              nullptr, 0, d_bih1, d_bhh1, dg, 4096, -1);
        lstm_cell<<<4096, 256, 0, stream>>>(dg, cd1, hd1, nullptr, 1024);
        gemmf(1024, 384, hd1, 1024, 1024, op_w, 1024, nullptr, 0, 0, nullptr, 0,
              nullptr, 0, op_b, nullptr, out, 384, s);
    }
}